// Round 9
// baseline (203.691 us; speedup 1.0000x reference)
//
#include <hip/hip_runtime.h>
#include <hip/hip_bf16.h>

using bf16 = __hip_bfloat16;
typedef short bf16x8 __attribute__((ext_vector_type(8)));
typedef float f32x4 __attribute__((ext_vector_type(4)));
typedef unsigned short ushort8_t __attribute__((ext_vector_type(8)));
typedef unsigned uint4_t __attribute__((ext_vector_type(4)));
typedef unsigned long long u64;

static constexpr int NA_ = 2048, NB_ = 2048;
static constexpr int H_ = 8, DH_ = 64, INNER_ = 512;
static constexpr int MROWS = 2 * NA_;  // 4096 rows for both batches

#define MFMA32(a, b, c) __builtin_amdgcn_mfma_f32_16x16x32_bf16(a, b, c, 0, 0, 0)

#if __has_builtin(__builtin_amdgcn_exp2f)
#define EXP2(x) __builtin_amdgcn_exp2f(x)
#else
#define EXP2(x) exp2f(x)
#endif

__device__ __forceinline__ unsigned short bfbits(float x) {
  bf16 h = __float2bfloat16(x);
  return __builtin_bit_cast(unsigned short, h);
}
__device__ __forceinline__ float b2f(unsigned short u) {
  unsigned v = ((unsigned)u) << 16;
  return __builtin_bit_cast(float, v);
}

// pack two fp32 -> dword of 2 bf16 (lo=a, hi=b), round-half-up via +0x8000
__device__ __forceinline__ unsigned pkbf(float a, float b) {
  unsigned ua = __builtin_bit_cast(unsigned, a) + 0x8000u;
  unsigned ub = __builtin_bit_cast(unsigned, b) + 0x8000u;
#if __has_builtin(__builtin_amdgcn_perm)
  // d = [ua.b2, ua.b3, ub.b2, ub.b3]
  return __builtin_amdgcn_perm(ub, ua, 0x07060302u);
#else
  return (ua >> 16) | (ub & 0xFFFF0000u);
#endif
}

// ======== prep: ln_feat (blocks 0..2047) | wconv (2048..4607) | maskpack (4608..6655)
__global__ __launch_bounds__(256) void prep_kernel(
    const float* __restrict__ fa_in, const float* __restrict__ fb_in,
    const float* __restrict__ law, const float* __restrict__ lab,
    const float* __restrict__ lbw, const float* __restrict__ lbb,
    bf16* __restrict__ fa, bf16* __restrict__ fb,
    const float* __restrict__ Wq, const float* __restrict__ Wk,
    const float* __restrict__ Wv, const float* __restrict__ Wg,
    const float* __restrict__ Wo,
    bf16* __restrict__ Wqt, bf16* __restrict__ Wkt,
    bf16* __restrict__ Wvt, bf16* __restrict__ Wgt,
    bf16* __restrict__ Woth, bf16* __restrict__ Wotl,
    const void* __restrict__ maskp, u64* __restrict__ mbits) {
  int blk = blockIdx.x;
  int t = threadIdx.x;
  if (blk < 2048) {
    // ---- LN of feats, one wave per row ----
    int row = blk * 4 + (t >> 6);
    int lane = t & 63;
    const float *src, *w, *bb;
    bf16* dst;
    int r;
    if (row < MROWS) { src = fa_in; w = law; bb = lab; dst = fa; r = row; }
    else             { src = fb_in; w = lbw; bb = lbb; dst = fb; r = row - MROWS; }
    float4 x = *(const float4*)(src + (size_t)r * 256 + lane * 4);
    float s  = (x.x + x.y) + (x.z + x.w);
    float s2 = (x.x * x.x + x.y * x.y) + (x.z * x.z + x.w * x.w);
#pragma unroll
    for (int m = 32; m >= 1; m >>= 1) { s += __shfl_xor(s, m); s2 += __shfl_xor(s2, m); }
    float mean = s * (1.0f / 256.0f);
    float var  = s2 * (1.0f / 256.0f) - mean * mean;
    float rstd = rsqrtf(var + 1e-5f);
    float4 wv = *(const float4*)(w + lane * 4);
    float4 bv = *(const float4*)(bb + lane * 4);
    ushort4 o;
    o.x = bfbits((x.x - mean) * rstd * wv.x + bv.x);
    o.y = bfbits((x.y - mean) * rstd * wv.y + bv.y);
    o.z = bfbits((x.z - mean) * rstd * wv.z + bv.z);
    o.w = bfbits((x.w - mean) * rstd * wv.w + bv.w);
    *(ushort4*)(dst + (size_t)r * 256 + lane * 4) = o;
  } else if (blk < 4608) {
    // ---- weight convert/transpose ----
    int z = (blk - 2048) >> 9;
    int idx = ((blk - 2048) & 511) * 256 + t;  // 0..131071
    if (z < 4) {
      const float* W = (z == 0) ? Wq : (z == 1) ? Wk : (z == 2) ? Wv : Wg;
      bf16* Wt = (z == 0) ? Wqt : (z == 1) ? Wkt : (z == 2) ? Wvt : Wgt;
      int kk = idx >> 9, n = idx & 511;
      Wt[n * 256 + kk] = __float2bfloat16(W[idx]);
    } else {
      int kk = idx >> 8, n = idx & 255;
      float w = Wo[idx];
      bf16 hi = __float2bfloat16(w);
      Woth[n * 512 + kk] = hi;
      Wotl[n * 512 + kk] = __float2bfloat16(w - __bfloat162float(hi));
    }
  } else {
    // ---- mask bit-pack with per-block dtype self-detect ----
    __shared__ unsigned shf[4];
    const unsigned char* mu = (const unsigned char*)maskp;
    bool nz = ((t & 3) != 0) && (mu[t] != 0);
    u64 bal = __ballot(nz);
    if ((t & 63) == 0) shf[t >> 6] = (bal != 0ull) ? 1u : 0u;
    __syncthreads();
    bool m8 = (shf[0] | shf[1] | shf[2] | shf[3]) != 0;  // nonzero off-4 byte => u8
    int lane = t & 63, wid = t >> 6;
    int lb = blk - 4608;
    for (size_t word = (size_t)lb * 4 + wid; word < 131072; word += 8192) {
      size_t e = word * 64 + lane;
      int v = m8 ? (int)mu[e] : ((const int*)maskp)[e];
      u64 b2 = __ballot(v != 0);
      if (lane == 0) mbits[word] = b2;
    }
  }
}

// ======== all four pre-GEMMs in one launch: grid dim3(256,1,4) ========
// z=0: q = LN(fa@Wq+bq) * scale2 (attn scale folded in!)  z=1: k = LN(fb@Wk+bk)
// z=2: g = fa@Wg+bg (bf16 [M][512])  z=3: v^T layout (m-tile 128, n-tile 64)
__global__ __launch_bounds__(256) void gemm4_kernel(
    const bf16* __restrict__ fa, const bf16* __restrict__ fb,
    const bf16* __restrict__ Wqt, const bf16* __restrict__ Wkt,
    const bf16* __restrict__ Wgt, const bf16* __restrict__ Wvt,
    const float* __restrict__ bq, const float* __restrict__ bk,
    const float* __restrict__ bg, const float* __restrict__ bv,
    const float* __restrict__ qlw, const float* __restrict__ qlb,
    const float* __restrict__ klw, const float* __restrict__ klb,
    bf16* __restrict__ qo, bf16* __restrict__ ko,
    bf16* __restrict__ gout, bf16* __restrict__ vout) {
  __shared__ __align__(16) char sm[27648];
  int z = blockIdx.z;
  int t = threadIdx.x, wave = t >> 6, lane = t & 63;
  int lm = lane & 15, quad = lane >> 4, q8 = quad * 8;

  if (z < 2) {
    // ---------- q/k GEMM with fused LayerNorm ----------
    bf16* As = (bf16*)sm;                       // [16][264] = 8448 B
    float* Pred = (float*)(sm + 16896);         // [16][8]
    float* MV   = (float*)(sm + 17408);         // [16][2]
    const bf16* A    = z ? fb : fa;
    const bf16* Wt   = z ? Wkt : Wqt;
    const float* bias = z ? bk : bq;
    const float* lw  = z ? klw : qlw;
    const float* lb  = z ? klb : qlb;
    bf16* out        = z ? ko : qo;
    int m0 = blockIdx.x * 16;
    // stage A 16x256 (stride 264 B-aligned 16)
#pragma unroll
    for (int i = 0; i < 2; i++) {
      int id = t + 256 * i, r = id >> 5, cg = id & 31;
      *(ushort8_t*)(&As[r * 264 + cg * 8]) =
          *(const ushort8_t*)(A + (size_t)(m0 + r) * 256 + cg * 8);
    }
    __syncthreads();
    int n0w = wave * 128;
    f32x4 acc[8] = {};
    const bf16* wrow[8];
#pragma unroll
    for (int ni = 0; ni < 8; ni++) wrow[ni] = Wt + (size_t)(n0w + ni * 16 + lm) * 256;
#pragma unroll
    for (int ks = 0; ks < 8; ks++) {
      int k0 = ks * 32;
      bf16x8 af = *(const bf16x8*)(&As[lm * 264 + k0 + q8]);
#pragma unroll
      for (int ni = 0; ni < 8; ni++) {
        bf16x8 bf_ = *(const bf16x8*)(wrow[ni] + k0 + q8);
        acc[ni] = MFMA32(af, bf_, acc[ni]);
      }
    }
    float bvv[8];
#pragma unroll
    for (int ni = 0; ni < 8; ni++) bvv[ni] = bias[n0w + ni * 16 + lm];
#pragma unroll
    for (int ni = 0; ni < 8; ni++)
#pragma unroll
      for (int r = 0; r < 4; r++) acc[ni][r] += bvv[ni];
    // per-row stats over the wave's 128 cols
#pragma unroll
    for (int r = 0; r < 4; r++) {
      float s = 0.f, s2 = 0.f;
#pragma unroll
      for (int ni = 0; ni < 8; ni++) { s += acc[ni][r]; s2 += acc[ni][r] * acc[ni][r]; }
#pragma unroll
      for (int m = 1; m <= 8; m <<= 1) { s += __shfl_xor(s, m); s2 += __shfl_xor(s2, m); }
      if (lm == 0) {
        int row = quad * 4 + r;
        Pred[row * 8 + wave * 2]     = s;
        Pred[row * 8 + wave * 2 + 1] = s2;
      }
    }
    __syncthreads();
    if (t < 16) {
      float s = 0.f, s2 = 0.f;
#pragma unroll
      for (int w = 0; w < 4; w++) { s += Pred[t * 8 + w * 2]; s2 += Pred[t * 8 + w * 2 + 1]; }
      float mean = s * (1.0f / 512.0f);
      float var  = s2 * (1.0f / 512.0f) - mean * mean;
      MV[t * 2]     = mean;
      MV[t * 2 + 1] = rsqrtf(var + 1e-5f);
    }
    __syncthreads();
    float lww[8], lbb_[8];
#pragma unroll
    for (int ni = 0; ni < 8; ni++) {
      lww[ni]  = lw[n0w + ni * 16 + lm];
      lbb_[ni] = lb[n0w + ni * 16 + lm];
    }
    if (z == 0) {
      // fold attn scale (1/sqrt(dh) * log2(e)) into q so attn does p=exp2(s) raw
      const float SC = 0.125f * 1.44269504088896f;
#pragma unroll
      for (int ni = 0; ni < 8; ni++) { lww[ni] *= SC; lbb_[ni] *= SC; }
    }
#pragma unroll
    for (int r = 0; r < 4; r++) {
      int row = quad * 4 + r;
      float mean = MV[row * 2], rstd = MV[row * 2 + 1];
      size_t obase = (size_t)(m0 + row) * 512 + n0w;
#pragma unroll
      for (int ni = 0; ni < 8; ni++)
        out[obase + ni * 16 + lm] =
            __float2bfloat16((acc[ni][r] - mean) * rstd * lww[ni] + lbb_[ni]);
    }
  } else {
    // ---------- g/v GEMM: m-tile 128, n-tile 64 (stride 72, 16-B aligned) ----------
    bf16* As = (bf16*)sm;                 // [128][72] = 18432 B
    bf16* Bs = (bf16*)(sm + 18432);       // [64][72]  = 9216 B
    const bf16* A    = (z == 3) ? fb : fa;
    const bf16* Wt   = (z == 3) ? Wvt : Wgt;
    const float* bias = (z == 3) ? bv : bg;
    int x = blockIdx.x;
    int m0 = (x >> 3) * 128, n0 = (x & 7) * 64;
    int wm = wave * 32;
    f32x4 acc[2][4] = {};
    for (int k0 = 0; k0 < 256; k0 += 64) {
      __syncthreads();
#pragma unroll
      for (int i = 0; i < 4; i++) {
        int id = t + 256 * i, r = id >> 3, cg = id & 7;
        *(ushort8_t*)(&As[r * 72 + cg * 8]) =
            *(const ushort8_t*)(A + (size_t)(m0 + r) * 256 + k0 + cg * 8);
      }
#pragma unroll
      for (int i = 0; i < 2; i++) {
        int id = t + 256 * i, r = id >> 3, cg = id & 7;
        *(ushort8_t*)(&Bs[r * 72 + cg * 8]) =
            *(const ushort8_t*)(Wt + (size_t)(n0 + r) * 256 + k0 + cg * 8);
      }
      __syncthreads();
#pragma unroll
      for (int kk = 0; kk < 64; kk += 32) {
        bf16x8 af[2], bf_[4];
#pragma unroll
        for (int mi = 0; mi < 2; mi++)
          af[mi] = *(const bf16x8*)(&As[(wm + mi * 16 + lm) * 72 + kk + q8]);
#pragma unroll
        for (int ni = 0; ni < 4; ni++)
          bf_[ni] = *(const bf16x8*)(&Bs[(ni * 16 + lm) * 72 + kk + q8]);
#pragma unroll
        for (int mi = 0; mi < 2; mi++)
#pragma unroll
          for (int ni = 0; ni < 4; ni++)
            acc[mi][ni] = MFMA32(af[mi], bf_[ni], acc[mi][ni]);
      }
    }
    if (z == 2) {
#pragma unroll
      for (int mi = 0; mi < 2; mi++)
#pragma unroll
        for (int ni = 0; ni < 4; ni++) {
          int nn = n0 + ni * 16 + lm;
          float bvv = bias[nn];
          int mb = m0 + wm + mi * 16 + quad * 4;
#pragma unroll
          for (int r = 0; r < 4; r++)
            gout[(size_t)(mb + r) * 512 + nn] = __float2bfloat16(acc[mi][ni][r] + bvv);
        }
    } else {
      // v^T: bounce through LDS [64 d][136] for coalesced [d][j] write
      __syncthreads();
      bf16* buf = (bf16*)sm;
#pragma unroll
      for (int mi = 0; mi < 2; mi++)
#pragma unroll
        for (int ni = 0; ni < 4; ni++) {
          int d_local = ni * 16 + lm;
          float bvv = bias[n0 + d_local];
          int j_local = wm + mi * 16 + quad * 4;
#pragma unroll
          for (int r = 0; r < 4; r++)
            buf[d_local * 136 + j_local + r] = __float2bfloat16(acc[mi][ni][r] + bvv);
        }
      __syncthreads();
      int bidx2 = m0 >> 11, j0g = m0 & 2047, hh = n0 >> 6;
      int dl = t >> 2, jseg = (t & 3) * 32;
      bf16* dstrow = vout + (size_t)((bidx2 * 8 + hh) * 64 + dl) * 2048 + j0g + jseg;
#pragma unroll
      for (int c = 0; c < 4; c++)
        *(ushort8_t*)(dstrow + c * 8) = *(const ushort8_t*)(&buf[dl * 136 + jseg + c * 8]);
    }
  }
}

// ---------------- flash attention: R4 EXACT (189.2-proven) + setprio -----------
// 8 waves = (wj in {0,1}: 32-j slice, wi in 0..3: 16-i rows); ONE shared 64-j
// K/V tile per iter, 32 iters. LDS: Q 9216 + 2x(K+V) dbuf 36864 + Lbuf = 46592.
// Per iter: write NEXT tile into alt buffer (off critical path), issue global
// loads 2 tiles ahead, compute current, ONE barrier. K sigma-permuted per
// 32-row group -> QK^T C-regs pack directly into k32 PV A-frag (P never
// touches LDS). l on matrix pipe. XCD swizzle: each XCD owns 2 whole bh.
// Epilogue: 2-way O merge + distributed 8-wave write.
// ONLY delta vs R4: s_setprio(1/0) around the MFMA clusters (T5).
__global__ __launch_bounds__(512, 4) void attn_kernel(
    const bf16* __restrict__ q, const bf16* __restrict__ k,
    const bf16* __restrict__ vt, const bf16* __restrict__ g,
    const u64* __restrict__ mbits,
    bf16* __restrict__ gh, bf16* __restrict__ gl) {
  __shared__ __align__(16) char smem[46592];
  bf16* Qs = (bf16*)smem;                    // 64*72 bf16 = 9216 B
  bf16* KVB = (bf16*)(smem + 9216);          // 2 bufs x (K 4608 + V 4608 elems)
  float* Om = (float*)(smem + 9216);         // epilogue overlay: 64*66*4 = 16896 B
  float* Lbuf = (float*)(smem + 46080);      // 2*64 floats = 512 B
  constexpr int BUFE = 2 * 64 * 72;          // elems per dbuf slot

  // XCD-locality swizzle: flat dispatch id -> each XCD gets 2 whole bh
  int flat = blockIdx.y * 32 + blockIdx.x;
  int bh = (flat & 7) * 2 + (flat >> 8);
  int qt = (flat >> 3) & 31;
  int bidx = bh >> 3, h = bh & 7;
  int i0 = qt * 64;
  int t = threadIdx.x, wave = t >> 6, lane = t & 63;
  int wj = wave >> 2, wi = wave & 3;
  int lm = lane & 15, quad = lane >> 4, q8 = quad * 8;
  int wj32 = wj * 32, wi16 = wi * 16;
  int srow = t >> 3, scg = (t & 7) * 8;      // staging row/col (64 rows x 8 cgs)

  // sigma-permuted K staging row (within each 32-row group)
  int sg = srow & 31;
  int ksrow = (srow & 32) + (((sg & 4) << 2) | ((sg & 24) >> 1) | (sg & 3));
  int ksl = ksrow * 72 + scg;
  int vsl = srow * 72 + scg;

  const bf16* kb = k + (size_t)(bidx * NB_) * INNER_ + h * DH_;
  const bf16* vb = vt + (size_t)(bh * DH_) * NB_;
  const bf16* ksrc = kb + (size_t)srow * INNER_ + scg;
  const bf16* vsrc = vb + (size_t)srow * NB_ + scg;

  // stage Q tile (64 x 64), one shot
  *(ushort8_t*)(&Qs[srow * 72 + scg]) =
      *(const ushort8_t*)(q + (size_t)(bidx * NA_ + i0 + srow) * INNER_ + h * DH_ + scg);

  // preload tile 0 into regs
  ushort8_t kr = *(const ushort8_t*)(ksrc);
  ushort8_t vr = *(const ushort8_t*)(vsrc);

  __syncthreads();  // Q staged
  bf16x8 bq0 = *(const bf16x8*)(&Qs[(wi16 + lm) * 72 + q8]);
  bf16x8 bq1 = *(const bf16x8*)(&Qs[(wi16 + lm) * 72 + 32 + q8]);

  // write tile 0 into buf 0
  *(ushort8_t*)(&KVB[ksl]) = kr;
  *(ushort8_t*)(&KVB[64 * 72 + vsl]) = vr;
  // preload tile 1
  kr = *(const ushort8_t*)(ksrc + 64 * INNER_);
  vr = *(const ushort8_t*)(vsrc + 64);

  // constant B fragment: ones-column at n=0 (bf16 1.0 = 0x3F80)
  bf16x8 bone;
  {
    short onev = (lm == 0) ? (short)0x3F80 : (short)0;
#pragma unroll
    for (int i = 0; i < 8; i++) bone[i] = onev;
  }

  f32x4 oacc[4] = {};
  f32x4 lacc = {};  // l at lanes lm==0, i_local = quad*4+r

  const u64* mrp = mbits + (size_t)(bidx * NA_ + i0 + wi16 + lm) * (NB_ / 64);
  int shp = wj32 + quad * 8;
  u64 smw = mrp[0] >> shp;

  __syncthreads();  // buf0 ready

  for (int it = 0; it < 32; it++) {
    bf16* Ks = KVB + (it & 1) * BUFE;
    bf16* Vs = Ks + 64 * 72;
    // write NEXT tile into alt buffer (overlaps compute; off critical path)
    if (it < 31) {
      bf16* Kn = KVB + ((it + 1) & 1) * BUFE;
      *(ushort8_t*)(&Kn[ksl]) = kr;
      *(ushort8_t*)(&Kn[64 * 72 + vsl]) = vr;
    }
    // issue global loads 2 tiles ahead
    if (it < 30) {
      kr = *(const ushort8_t*)(ksrc + (size_t)(it + 2) * (64 * INNER_));
      vr = *(const ushort8_t*)(vsrc + (it + 2) * 64);
    }
    u64 nm = (it < 31) ? (mrp[it + 1] >> shp) : 0;

    // QK^T over the wave's 32-j slice (sigma-permuted staged rows)
    bf16x8 a00 = *(const bf16x8*)(&Ks[(wj32 + lm) * 72 + q8]);
    bf16x8 a01 = *(const bf16x8*)(&Ks[(wj32 + lm) * 72 + 32 + q8]);
    bf16x8 a10 = *(const bf16x8*)(&Ks[(wj32 + 16 + lm) * 72 + q8]);
    bf16x8 a11 = *(const bf16x8*)(&Ks[(wj32 + 16 + lm) * 72 + 32 + q8]);
    __builtin_amdgcn_s_setprio(1);
    f32x4 st0 = {0.f, 0.f, 0.f, 0.f}, st1 = {0.f, 0.f, 0.f, 0.f};
    st0 = MFMA32(a00, bq0, st0);
    st0 = MFMA32(a01, bq1, st0);
    st1 = MFMA32(a10, bq0, st1);
    st1 = MFMA32(a11, bq1, st1);
    __builtin_amdgcn_s_setprio(0);

    // p = exp2(masked s); lane's j = wj32 + quad*8 + js*4 + r -> bit js*4+r
    float p0[4], p1[4];
#pragma unroll
    for (int r = 0; r < 4; r++) {
      p0[r] = EXP2(((smw >> r) & 1ull) ? st0[r] : -200.0f);
      p1[r] = EXP2(((smw >> (4 + r)) & 1ull) ? st1[r] : -200.0f);
    }

    // pack into the k32 PV A-fragment (P register-only)
    uint4_t u0;
    u0[0] = pkbf(p0[0], p0[1]);
    u0[1] = pkbf(p0[2], p0[3]);
    u0[2] = pkbf(p1[0], p1[1]);
    u0[3] = pkbf(p1[2], p1[3]);
    bf16x8 pa = __builtin_bit_cast(bf16x8, u0);

    // PV: A = P [m=i][k=j32], B = V^T [n=d][k=j] -> O[i][d]
    __builtin_amdgcn_s_setprio(1);
#pragma unroll
    for (int c = 0; c < 4; c++) {
      bf16x8 v_ = *(const bf16x8*)(&Vs[(c * 16 + lm) * 72 + wj32 + q8]);
      oacc[c] = MFMA32(pa, v_, oacc[c]);
    }
    lacc = MFMA32(pa, bone, lacc);
    __builtin_amdgcn_s_setprio(0);

    smw = nm;
    __syncthreads();  // end of iter: alt-buffer writes visible, cur reads done
  }

  // -------- epilogue: 2-way merge (wj partners) + distributed write --------
  if (lm == 0) {
#pragma unroll
    for (int r = 0; r < 4; r++)
      Lbuf[wj * 64 + wi16 + quad * 4 + r] = lacc[r];
  }
  if (wj == 1) {
#pragma unroll
    for (int c = 0; c < 4; c++)
#pragma unroll
      for (int r = 0; r < 4; r++)
        Om[(wi16 + quad * 4 + r) * 66 + c * 16 + lm] = oacc[c][r];
  }
  __syncthreads();
  if (wj == 0) {
#pragma unroll
    for (int c = 0; c < 4; c++)
#pragma unroll
      for (int r = 0; r < 4; r++)
        Om[(wi16 + quad * 4 + r) * 66 + c * 16 + lm] += oacc[c][r];
  }
  __syncthreads();
  // final write: wave w -> rows w*8..w*8+7; thread: 8 consecutive cols
  {
    int row = wave * 8 + (lane >> 3);
    int col = (lane & 7) * 8;
    float l = Lbuf[row] + Lbuf[64 + row];
    float inv = 1.0f / l;
    size_t idx = (size_t)(bidx * NA_ + i0 + row) * INNER_ + h * DH_ + col;
    ushort8_t gv = *(const ushort8_t*)(g + idx);
    ushort8_t oh, ol;
#pragma unroll
    for (int e = 0; e < 8; e++) {
      float o = Om[row * 66 + col + e];
      float gf = b2f((unsigned short)gv[e]);
      float sig = 1.0f / (1.0f + __expf(-gf));
      float val = o * inv * sig;
      unsigned short hb = bfbits(val);
      oh[e] = hb;
      ol[e] = bfbits(val - b2f(hb));
    }
    *(ushort8_t*)(gh + idx) = oh;
    *(ushort8_t*)(gl + idx) = ol;
  }
}

// ---------------- final GEMM in split-bf16: A-LDS-once + B-global-direct --------
// grid dim3(2,256) = 512 blocks, 256 thr: 16-row m-tile (full K=512 staged hi+lo
// in LDS ONCE -> one barrier total), 128-col n-tile (wave owns 32 N). B frags
// read DIRECT from global (Woth/Wotl L2-resident, gemm4-q/k-proven pattern).
// Per wave: 96 MFMA vs 32 LDS reads + 64 global reads (was 96:96 LDS + 16 barriers).
__global__ __launch_bounds__(256) void gemm_split_kernel(
    const bf16* __restrict__ Ah, const bf16* __restrict__ Al,
    const bf16* __restrict__ Bh, const bf16* __restrict__ Bl,
    const float* __restrict__ bias, float* __restrict__ C) {
  constexpr int K = 512, N = 256;
  __shared__ __align__(16) bf16 Ash[16 * 520];   // 16640 B (pad 8: 2-way bank, free)
  __shared__ __align__(16) bf16 Asl[16 * 520];
  int n0 = blockIdx.x * 128, m0 = blockIdx.y * 16;
  int t = threadIdx.x, wave = t >> 6, lane = t & 63;
  int lm = lane & 15, quad = lane >> 4, q8 = quad * 8;
  // stage A hi/lo 16x512 once: 256 thr x 8 elem -> 4 chunks per buffer
#pragma unroll
  for (int i = 0; i < 4; i++) {
    int id = t + 256 * i, r = id >> 6, cg = id & 63;
    size_t ga = (size_t)(m0 + r) * K + cg * 8;
    *(ushort8_t*)(&Ash[r * 520 + cg * 8]) = *(const ushort8_t*)(Ah + ga);
    *(ushort8_t*)(&Asl[r * 520 + cg * 8]) = *(const ushort8_t*)(Al + ga);
  }
  __syncthreads();
  int n0w = n0 + wave * 32;
  f32x4 acc[2] = {};
  const bf16* bhrow[2];
  const bf16* blrow[2];
#pragma unroll
  for (int ni = 0; ni < 2; ni++) {
    bhrow[ni] = Bh + (size_t)(n0w + ni * 16 + lm) * K;
    blrow[ni] = Bl + (size_t)(n0w + ni * 16 + lm) * K;
  }
#pragma unroll
  for (int ks = 0; ks < 16; ks++) {
    int k0 = ks * 32;
    bf16x8 ah = *(const bf16x8*)(&Ash[lm * 520 + k0 + q8]);
    bf16x8 al = *(const bf16x8*)(&Asl[lm * 520 + k0 + q8]);
#pragma unroll
    for (int ni = 0; ni < 2; ni++) {
      bf16x8 bh_ = *(const bf16x8*)(bhrow[ni] + k0 + q8);
      bf16x8 bl_ = *(const bf16x8*)(blrow[ni] + k0 + q8);
      acc[ni] = MFMA32(ah, bh_, acc[ni]);
      acc[ni] = MFMA32(ah, bl_, acc[ni]);
      acc[ni] = MFMA32(al, bh_, acc[ni]);
    }
  }
#pragma unroll
  for (int ni = 0; ni < 2; ni++) {
    int n = n0w + ni * 16 + lm;
    float bvv = bias[n];
    int mb = m0 + quad * 4;
#pragma unroll
    for (int r = 0; r < 4; r++) C[(size_t)(mb + r) * N + n] = acc[ni][r] + bvv;
  }
}

extern "C" void kernel_launch(void* const* d_in, const int* in_sizes, int n_in,
                              void* d_out, int out_size, void* d_ws, size_t ws_size,
                              hipStream_t stream) {
  const float* feat_a = (const float*)d_in[0];
  const float* feat_b = (const float*)d_in[1];
  const void*  mask   = d_in[2];
  const float* Wq = (const float*)d_in[3];
  const float* bq = (const float*)d_in[4];
  const float* Wk = (const float*)d_in[5];
  const float* bk = (const float*)d_in[6];
  const float* Wv = (const float*)d_in[7];
  const float* bv = (const float*)d_in[8];
  const float* Wg = (const float*)d_in[9];
  const float* bg = (const float*)d_in[10];
  const float* Wo = (const float*)d_in[11];
  const float* bo = (const float*)d_in[12];
  const float* law = (const float*)d_in[13];
  const float* lab = (const float*)d_in[14];
  const float* lbw = (const float*)d_in[15];
  const float* lbb = (const float*)d_in[16];
  const float* qlw = (const float*)d_in[17];
  const float* qlb = (const float*)d_in[18];
  const float* klw = (const float*)d_in[19];
  const float* klb = (const float*)d_in[20];

  char* ws = (char*)d_ws;
  size_t off = 0;
  auto alloc = [&](size_t bytes) -> void* {
    void* p = ws + off;
    off += (bytes + 255) & ~(size_t)255;
    return p;
  };
  bf16* fa    = (bf16*)alloc((size_t)MROWS * 256 * 2);
  bf16* fb    = (bf16*)alloc((size_t)MROWS * 256 * 2);
  bf16* Wqt   = (bf16*)alloc((size_t)131072 * 2);
  bf16* Wkt   = (bf16*)alloc((size_t)131072 * 2);
  bf16* Wvt   = (bf16*)alloc((size_t)131072 * 2);
  bf16* Wgt   = (bf16*)alloc((size_t)131072 * 2);
  bf16* Woth  = (bf16*)alloc((size_t)131072 * 2);
  bf16* Wotl  = (bf16*)alloc((size_t)131072 * 2);
  bf16* qb_   = (bf16*)alloc((size_t)MROWS * 512 * 2);
  bf16* kb_   = (bf16*)alloc((size_t)MROWS * 512 * 2);
  bf16* vtb   = (bf16*)alloc((size_t)1024 * 2048 * 2);
  bf16* gbuf  = (bf16*)alloc((size_t)MROWS * 512 * 2);
  bf16* gh    = (bf16*)alloc((size_t)MROWS * 512 * 2);
  bf16* gl    = (bf16*)alloc((size_t)MROWS * 512 * 2);
  u64*  mbits = (u64*)alloc((size_t)131072 * 8);

  prep_kernel<<<6656, 256, 0, stream>>>(
      feat_a, feat_b, law, lab, lbw, lbb, fa, fb,
      Wq, Wk, Wv, Wg, Wo, Wqt, Wkt, Wvt, Wgt, Woth, Wotl, mask, mbits);
  gemm4_kernel<<<dim3(256, 1, 4), 256, 0, stream>>>(
      fa, fb, Wqt, Wkt, Wgt, Wvt, bq, bk, bg, bv,
      qlw, qlb, klw, klb, qb_, kb_, gbuf, vtb);
  attn_kernel<<<dim3(32, 16), 512, 0, stream>>>(qb_, kb_, vtb, gbuf, mbits, gh, gl);
  gemm_split_kernel<<<dim3(2, 256), 256, 0, stream>>>(gh, gl, Woth, Wotl, bo, (float*)d_out);
}

// Round 10
// 188.816 us; speedup vs baseline: 1.0788x; 1.0788x over previous
//
#include <hip/hip_runtime.h>
#include <hip/hip_bf16.h>

using bf16 = __hip_bfloat16;
typedef short bf16x8 __attribute__((ext_vector_type(8)));
typedef float f32x4 __attribute__((ext_vector_type(4)));
typedef unsigned short ushort8_t __attribute__((ext_vector_type(8)));
typedef unsigned uint4_t __attribute__((ext_vector_type(4)));
typedef unsigned long long u64;

static constexpr int NA_ = 2048, NB_ = 2048;
static constexpr int H_ = 8, DH_ = 64, INNER_ = 512;
static constexpr int MROWS = 2 * NA_;  // 4096 rows for both batches

#define MFMA32(a, b, c) __builtin_amdgcn_mfma_f32_16x16x32_bf16(a, b, c, 0, 0, 0)

#if __has_builtin(__builtin_amdgcn_exp2f)
#define EXP2(x) __builtin_amdgcn_exp2f(x)
#else
#define EXP2(x) exp2f(x)
#endif

__device__ __forceinline__ unsigned short bfbits(float x) {
  bf16 h = __float2bfloat16(x);
  return __builtin_bit_cast(unsigned short, h);
}
__device__ __forceinline__ float b2f(unsigned short u) {
  unsigned v = ((unsigned)u) << 16;
  return __builtin_bit_cast(float, v);
}

// pack two fp32 -> dword of 2 bf16 (lo=a, hi=b), round-half-up via +0x8000
__device__ __forceinline__ unsigned pkbf(float a, float b) {
  unsigned ua = __builtin_bit_cast(unsigned, a) + 0x8000u;
  unsigned ub = __builtin_bit_cast(unsigned, b) + 0x8000u;
#if __has_builtin(__builtin_amdgcn_perm)
  // d = [ua.b2, ua.b3, ub.b2, ub.b3]
  return __builtin_amdgcn_perm(ub, ua, 0x07060302u);
#else
  return (ua >> 16) | (ub & 0xFFFF0000u);
#endif
}

// ======== prep: ln_feat (blocks 0..2047) | wconv (2048..4607) | maskpack (4608..6655)
__global__ __launch_bounds__(256) void prep_kernel(
    const float* __restrict__ fa_in, const float* __restrict__ fb_in,
    const float* __restrict__ law, const float* __restrict__ lab,
    const float* __restrict__ lbw, const float* __restrict__ lbb,
    bf16* __restrict__ fa, bf16* __restrict__ fb,
    const float* __restrict__ Wq, const float* __restrict__ Wk,
    const float* __restrict__ Wv, const float* __restrict__ Wg,
    const float* __restrict__ Wo,
    bf16* __restrict__ Wqt, bf16* __restrict__ Wkt,
    bf16* __restrict__ Wvt, bf16* __restrict__ Wgt,
    bf16* __restrict__ Woth, bf16* __restrict__ Wotl,
    const void* __restrict__ maskp, u64* __restrict__ mbits) {
  int blk = blockIdx.x;
  int t = threadIdx.x;
  if (blk < 2048) {
    // ---- LN of feats, one wave per row ----
    int row = blk * 4 + (t >> 6);
    int lane = t & 63;
    const float *src, *w, *bb;
    bf16* dst;
    int r;
    if (row < MROWS) { src = fa_in; w = law; bb = lab; dst = fa; r = row; }
    else             { src = fb_in; w = lbw; bb = lbb; dst = fb; r = row - MROWS; }
    float4 x = *(const float4*)(src + (size_t)r * 256 + lane * 4);
    float s  = (x.x + x.y) + (x.z + x.w);
    float s2 = (x.x * x.x + x.y * x.y) + (x.z * x.z + x.w * x.w);
#pragma unroll
    for (int m = 32; m >= 1; m >>= 1) { s += __shfl_xor(s, m); s2 += __shfl_xor(s2, m); }
    float mean = s * (1.0f / 256.0f);
    float var  = s2 * (1.0f / 256.0f) - mean * mean;
    float rstd = rsqrtf(var + 1e-5f);
    float4 wv = *(const float4*)(w + lane * 4);
    float4 bv = *(const float4*)(bb + lane * 4);
    ushort4 o;
    o.x = bfbits((x.x - mean) * rstd * wv.x + bv.x);
    o.y = bfbits((x.y - mean) * rstd * wv.y + bv.y);
    o.z = bfbits((x.z - mean) * rstd * wv.z + bv.z);
    o.w = bfbits((x.w - mean) * rstd * wv.w + bv.w);
    *(ushort4*)(dst + (size_t)r * 256 + lane * 4) = o;
  } else if (blk < 4608) {
    // ---- weight convert/transpose ----
    int z = (blk - 2048) >> 9;
    int idx = ((blk - 2048) & 511) * 256 + t;  // 0..131071
    if (z < 4) {
      const float* W = (z == 0) ? Wq : (z == 1) ? Wk : (z == 2) ? Wv : Wg;
      bf16* Wt = (z == 0) ? Wqt : (z == 1) ? Wkt : (z == 2) ? Wvt : Wgt;
      int kk = idx >> 9, n = idx & 511;
      Wt[n * 256 + kk] = __float2bfloat16(W[idx]);
    } else {
      int kk = idx >> 8, n = idx & 255;
      float w = Wo[idx];
      bf16 hi = __float2bfloat16(w);
      Woth[n * 512 + kk] = hi;
      Wotl[n * 512 + kk] = __float2bfloat16(w - __bfloat162float(hi));
    }
  } else {
    // ---- mask bit-pack with per-block dtype self-detect ----
    __shared__ unsigned shf[4];
    const unsigned char* mu = (const unsigned char*)maskp;
    bool nz = ((t & 3) != 0) && (mu[t] != 0);
    u64 bal = __ballot(nz);
    if ((t & 63) == 0) shf[t >> 6] = (bal != 0ull) ? 1u : 0u;
    __syncthreads();
    bool m8 = (shf[0] | shf[1] | shf[2] | shf[3]) != 0;  // nonzero off-4 byte => u8
    int lane = t & 63, wid = t >> 6;
    int lb = blk - 4608;
    for (size_t word = (size_t)lb * 4 + wid; word < 131072; word += 8192) {
      size_t e = word * 64 + lane;
      int v = m8 ? (int)mu[e] : ((const int*)maskp)[e];
      u64 b2 = __ballot(v != 0);
      if (lane == 0) mbits[word] = b2;
    }
  }
}

// ======== all four pre-GEMMs in one launch: grid dim3(256,1,4) ========
// z=0: q = LN(fa@Wq+bq) * scale2 (attn scale folded in!)  z=1: k = LN(fb@Wk+bk)
// z=2: g = fa@Wg+bg (bf16 [M][512])  z=3: v^T layout (m-tile 128, n-tile 64)
__global__ __launch_bounds__(256) void gemm4_kernel(
    const bf16* __restrict__ fa, const bf16* __restrict__ fb,
    const bf16* __restrict__ Wqt, const bf16* __restrict__ Wkt,
    const bf16* __restrict__ Wgt, const bf16* __restrict__ Wvt,
    const float* __restrict__ bq, const float* __restrict__ bk,
    const float* __restrict__ bg, const float* __restrict__ bv,
    const float* __restrict__ qlw, const float* __restrict__ qlb,
    const float* __restrict__ klw, const float* __restrict__ klb,
    bf16* __restrict__ qo, bf16* __restrict__ ko,
    bf16* __restrict__ gout, bf16* __restrict__ vout) {
  __shared__ __align__(16) char sm[27648];
  int z = blockIdx.z;
  int t = threadIdx.x, wave = t >> 6, lane = t & 63;
  int lm = lane & 15, quad = lane >> 4, q8 = quad * 8;

  if (z < 2) {
    // ---------- q/k GEMM with fused LayerNorm ----------
    bf16* As = (bf16*)sm;                       // [16][264] = 8448 B
    float* Pred = (float*)(sm + 16896);         // [16][8]
    float* MV   = (float*)(sm + 17408);         // [16][2]
    const bf16* A    = z ? fb : fa;
    const bf16* Wt   = z ? Wkt : Wqt;
    const float* bias = z ? bk : bq;
    const float* lw  = z ? klw : qlw;
    const float* lb  = z ? klb : qlb;
    bf16* out        = z ? ko : qo;
    int m0 = blockIdx.x * 16;
    // stage A 16x256 (stride 264 B-aligned 16)
#pragma unroll
    for (int i = 0; i < 2; i++) {
      int id = t + 256 * i, r = id >> 5, cg = id & 31;
      *(ushort8_t*)(&As[r * 264 + cg * 8]) =
          *(const ushort8_t*)(A + (size_t)(m0 + r) * 256 + cg * 8);
    }
    __syncthreads();
    int n0w = wave * 128;
    f32x4 acc[8] = {};
    const bf16* wrow[8];
#pragma unroll
    for (int ni = 0; ni < 8; ni++) wrow[ni] = Wt + (size_t)(n0w + ni * 16 + lm) * 256;
#pragma unroll
    for (int ks = 0; ks < 8; ks++) {
      int k0 = ks * 32;
      bf16x8 af = *(const bf16x8*)(&As[lm * 264 + k0 + q8]);
#pragma unroll
      for (int ni = 0; ni < 8; ni++) {
        bf16x8 bf_ = *(const bf16x8*)(wrow[ni] + k0 + q8);
        acc[ni] = MFMA32(af, bf_, acc[ni]);
      }
    }
    float bvv[8];
#pragma unroll
    for (int ni = 0; ni < 8; ni++) bvv[ni] = bias[n0w + ni * 16 + lm];
#pragma unroll
    for (int ni = 0; ni < 8; ni++)
#pragma unroll
      for (int r = 0; r < 4; r++) acc[ni][r] += bvv[ni];
    // per-row stats over the wave's 128 cols
#pragma unroll
    for (int r = 0; r < 4; r++) {
      float s = 0.f, s2 = 0.f;
#pragma unroll
      for (int ni = 0; ni < 8; ni++) { s += acc[ni][r]; s2 += acc[ni][r] * acc[ni][r]; }
#pragma unroll
      for (int m = 1; m <= 8; m <<= 1) { s += __shfl_xor(s, m); s2 += __shfl_xor(s2, m); }
      if (lm == 0) {
        int row = quad * 4 + r;
        Pred[row * 8 + wave * 2]     = s;
        Pred[row * 8 + wave * 2 + 1] = s2;
      }
    }
    __syncthreads();
    if (t < 16) {
      float s = 0.f, s2 = 0.f;
#pragma unroll
      for (int w = 0; w < 4; w++) { s += Pred[t * 8 + w * 2]; s2 += Pred[t * 8 + w * 2 + 1]; }
      float mean = s * (1.0f / 512.0f);
      float var  = s2 * (1.0f / 512.0f) - mean * mean;
      MV[t * 2]     = mean;
      MV[t * 2 + 1] = rsqrtf(var + 1e-5f);
    }
    __syncthreads();
    float lww[8], lbb_[8];
#pragma unroll
    for (int ni = 0; ni < 8; ni++) {
      lww[ni]  = lw[n0w + ni * 16 + lm];
      lbb_[ni] = lb[n0w + ni * 16 + lm];
    }
    if (z == 0) {
      // fold attn scale (1/sqrt(dh) * log2(e)) into q so attn does p=exp2(s) raw
      const float SC = 0.125f * 1.44269504088896f;
#pragma unroll
      for (int ni = 0; ni < 8; ni++) { lww[ni] *= SC; lbb_[ni] *= SC; }
    }
#pragma unroll
    for (int r = 0; r < 4; r++) {
      int row = quad * 4 + r;
      float mean = MV[row * 2], rstd = MV[row * 2 + 1];
      size_t obase = (size_t)(m0 + row) * 512 + n0w;
#pragma unroll
      for (int ni = 0; ni < 8; ni++)
        out[obase + ni * 16 + lm] =
            __float2bfloat16((acc[ni][r] - mean) * rstd * lww[ni] + lbb_[ni]);
    }
  } else {
    // ---------- g/v GEMM: m-tile 128, n-tile 64 (stride 72, 16-B aligned) ----------
    bf16* As = (bf16*)sm;                 // [128][72] = 18432 B
    bf16* Bs = (bf16*)(sm + 18432);       // [64][72]  = 9216 B
    const bf16* A    = (z == 3) ? fb : fa;
    const bf16* Wt   = (z == 3) ? Wvt : Wgt;
    const float* bias = (z == 3) ? bv : bg;
    int x = blockIdx.x;
    int m0 = (x >> 3) * 128, n0 = (x & 7) * 64;
    int wm = wave * 32;
    f32x4 acc[2][4] = {};
    for (int k0 = 0; k0 < 256; k0 += 64) {
      __syncthreads();
#pragma unroll
      for (int i = 0; i < 4; i++) {
        int id = t + 256 * i, r = id >> 3, cg = id & 7;
        *(ushort8_t*)(&As[r * 72 + cg * 8]) =
            *(const ushort8_t*)(A + (size_t)(m0 + r) * 256 + k0 + cg * 8);
      }
#pragma unroll
      for (int i = 0; i < 2; i++) {
        int id = t + 256 * i, r = id >> 3, cg = id & 7;
        *(ushort8_t*)(&Bs[r * 72 + cg * 8]) =
            *(const ushort8_t*)(Wt + (size_t)(n0 + r) * 256 + k0 + cg * 8);
      }
      __syncthreads();
#pragma unroll
      for (int kk = 0; kk < 64; kk += 32) {
        bf16x8 af[2], bf_[4];
#pragma unroll
        for (int mi = 0; mi < 2; mi++)
          af[mi] = *(const bf16x8*)(&As[(wm + mi * 16 + lm) * 72 + kk + q8]);
#pragma unroll
        for (int ni = 0; ni < 4; ni++)
          bf_[ni] = *(const bf16x8*)(&Bs[(ni * 16 + lm) * 72 + kk + q8]);
#pragma unroll
        for (int mi = 0; mi < 2; mi++)
#pragma unroll
          for (int ni = 0; ni < 4; ni++)
            acc[mi][ni] = MFMA32(af[mi], bf_[ni], acc[mi][ni]);
      }
    }
    if (z == 2) {
#pragma unroll
      for (int mi = 0; mi < 2; mi++)
#pragma unroll
        for (int ni = 0; ni < 4; ni++) {
          int nn = n0 + ni * 16 + lm;
          float bvv = bias[nn];
          int mb = m0 + wm + mi * 16 + quad * 4;
#pragma unroll
          for (int r = 0; r < 4; r++)
            gout[(size_t)(mb + r) * 512 + nn] = __float2bfloat16(acc[mi][ni][r] + bvv);
        }
    } else {
      // v^T: bounce through LDS [64 d][136] for coalesced [d][j] write
      __syncthreads();
      bf16* buf = (bf16*)sm;
#pragma unroll
      for (int mi = 0; mi < 2; mi++)
#pragma unroll
        for (int ni = 0; ni < 4; ni++) {
          int d_local = ni * 16 + lm;
          float bvv = bias[n0 + d_local];
          int j_local = wm + mi * 16 + quad * 4;
#pragma unroll
          for (int r = 0; r < 4; r++)
            buf[d_local * 136 + j_local + r] = __float2bfloat16(acc[mi][ni][r] + bvv);
        }
      __syncthreads();
      int bidx2 = m0 >> 11, j0g = m0 & 2047, hh = n0 >> 6;
      int dl = t >> 2, jseg = (t & 3) * 32;
      bf16* dstrow = vout + (size_t)((bidx2 * 8 + hh) * 64 + dl) * 2048 + j0g + jseg;
#pragma unroll
      for (int c = 0; c < 4; c++)
        *(ushort8_t*)(dstrow + c * 8) = *(const ushort8_t*)(&buf[dl * 136 + jseg + c * 8]);
    }
  }
}

// ---------------- flash attention: R4 EXACT (189.2-proven, no setprio) ---------
// 8 waves = (wj in {0,1}: 32-j slice, wi in 0..3: 16-i rows); ONE shared 64-j
// K/V tile per iter, 32 iters. LDS: Q 9216 + 2x(K+V) dbuf 36864 + Lbuf = 46592.
// Per iter: write NEXT tile into alt buffer (off critical path), issue global
// loads 2 tiles ahead, compute current, ONE barrier. K sigma-permuted per
// 32-row group (j=q*8+s*4+r at slot s*16+q*4+r) -> QK^T C-regs pack directly
// into the k32 PV A-fragment (P never touches LDS). l on matrix pipe.
// XCD swizzle: each XCD owns 2 whole bh -> K/V stay L2-resident.
// Epilogue: 2-way O merge + final write distributed over all 8 waves.
// LEDGER (do not re-try): setprio in this lockstep loop = NEGATIVE (R9);
// fatter 2-tile iters = -7us (R6); PV pipelining = -2us (R7); 4 blocks/CU
// 32-row tiles = -6us (R8); cross-block fence merge = disaster (R5).
__global__ __launch_bounds__(512, 4) void attn_kernel(
    const bf16* __restrict__ q, const bf16* __restrict__ k,
    const bf16* __restrict__ vt, const bf16* __restrict__ g,
    const u64* __restrict__ mbits,
    bf16* __restrict__ gh, bf16* __restrict__ gl) {
  __shared__ __align__(16) char smem[46592];
  bf16* Qs = (bf16*)smem;                    // 64*72 bf16 = 9216 B
  bf16* KVB = (bf16*)(smem + 9216);          // 2 bufs x (K 4608 + V 4608 elems)
  float* Om = (float*)(smem + 9216);         // epilogue overlay: 64*66*4 = 16896 B
  float* Lbuf = (float*)(smem + 46080);      // 2*64 floats = 512 B
  constexpr int BUFE = 2 * 64 * 72;          // elems per dbuf slot

  // XCD-locality swizzle: flat dispatch id -> each XCD gets 2 whole bh
  int flat = blockIdx.y * 32 + blockIdx.x;
  int bh = (flat & 7) * 2 + (flat >> 8);
  int qt = (flat >> 3) & 31;
  int bidx = bh >> 3, h = bh & 7;
  int i0 = qt * 64;
  int t = threadIdx.x, wave = t >> 6, lane = t & 63;
  int wj = wave >> 2, wi = wave & 3;
  int lm = lane & 15, quad = lane >> 4, q8 = quad * 8;
  int wj32 = wj * 32, wi16 = wi * 16;
  int srow = t >> 3, scg = (t & 7) * 8;      // staging row/col (64 rows x 8 cgs)

  // sigma-permuted K staging row (within each 32-row group)
  int sg = srow & 31;
  int ksrow = (srow & 32) + (((sg & 4) << 2) | ((sg & 24) >> 1) | (sg & 3));
  int ksl = ksrow * 72 + scg;
  int vsl = srow * 72 + scg;

  const bf16* kb = k + (size_t)(bidx * NB_) * INNER_ + h * DH_;
  const bf16* vb = vt + (size_t)(bh * DH_) * NB_;
  const bf16* ksrc = kb + (size_t)srow * INNER_ + scg;
  const bf16* vsrc = vb + (size_t)srow * NB_ + scg;

  // stage Q tile (64 x 64), one shot
  *(ushort8_t*)(&Qs[srow * 72 + scg]) =
      *(const ushort8_t*)(q + (size_t)(bidx * NA_ + i0 + srow) * INNER_ + h * DH_ + scg);

  // preload tile 0 into regs
  ushort8_t kr = *(const ushort8_t*)(ksrc);
  ushort8_t vr = *(const ushort8_t*)(vsrc);

  __syncthreads();  // Q staged
  bf16x8 bq0 = *(const bf16x8*)(&Qs[(wi16 + lm) * 72 + q8]);
  bf16x8 bq1 = *(const bf16x8*)(&Qs[(wi16 + lm) * 72 + 32 + q8]);

  // write tile 0 into buf 0
  *(ushort8_t*)(&KVB[ksl]) = kr;
  *(ushort8_t*)(&KVB[64 * 72 + vsl]) = vr;
  // preload tile 1
  kr = *(const ushort8_t*)(ksrc + 64 * INNER_);
  vr = *(const ushort8_t*)(vsrc + 64);

  // constant B fragment: ones-column at n=0 (bf16 1.0 = 0x3F80)
  bf16x8 bone;
  {
    short onev = (lm == 0) ? (short)0x3F80 : (short)0;
#pragma unroll
    for (int i = 0; i < 8; i++) bone[i] = onev;
  }

  f32x4 oacc[4] = {};
  f32x4 lacc = {};  // l at lanes lm==0, i_local = quad*4+r

  const u64* mrp = mbits + (size_t)(bidx * NA_ + i0 + wi16 + lm) * (NB_ / 64);
  int shp = wj32 + quad * 8;
  u64 smw = mrp[0] >> shp;

  __syncthreads();  // buf0 ready

  for (int it = 0; it < 32; it++) {
    bf16* Ks = KVB + (it & 1) * BUFE;
    bf16* Vs = Ks + 64 * 72;
    // write NEXT tile into alt buffer (overlaps compute; off critical path)
    if (it < 31) {
      bf16* Kn = KVB + ((it + 1) & 1) * BUFE;
      *(ushort8_t*)(&Kn[ksl]) = kr;
      *(ushort8_t*)(&Kn[64 * 72 + vsl]) = vr;
    }
    // issue global loads 2 tiles ahead
    if (it < 30) {
      kr = *(const ushort8_t*)(ksrc + (size_t)(it + 2) * (64 * INNER_));
      vr = *(const ushort8_t*)(vsrc + (it + 2) * 64);
    }
    u64 nm = (it < 31) ? (mrp[it + 1] >> shp) : 0;

    // QK^T over the wave's 32-j slice (sigma-permuted staged rows)
    bf16x8 a00 = *(const bf16x8*)(&Ks[(wj32 + lm) * 72 + q8]);
    bf16x8 a01 = *(const bf16x8*)(&Ks[(wj32 + lm) * 72 + 32 + q8]);
    bf16x8 a10 = *(const bf16x8*)(&Ks[(wj32 + 16 + lm) * 72 + q8]);
    bf16x8 a11 = *(const bf16x8*)(&Ks[(wj32 + 16 + lm) * 72 + 32 + q8]);
    f32x4 st0 = {0.f, 0.f, 0.f, 0.f}, st1 = {0.f, 0.f, 0.f, 0.f};
    st0 = MFMA32(a00, bq0, st0);
    st0 = MFMA32(a01, bq1, st0);
    st1 = MFMA32(a10, bq0, st1);
    st1 = MFMA32(a11, bq1, st1);

    // p = exp2(masked s); lane's j = wj32 + quad*8 + js*4 + r -> bit js*4+r
    float p0[4], p1[4];
#pragma unroll
    for (int r = 0; r < 4; r++) {
      p0[r] = EXP2(((smw >> r) & 1ull) ? st0[r] : -200.0f);
      p1[r] = EXP2(((smw >> (4 + r)) & 1ull) ? st1[r] : -200.0f);
    }

    // pack into the k32 PV A-fragment (P register-only)
    uint4_t u0;
    u0[0] = pkbf(p0[0], p0[1]);
    u0[1] = pkbf(p0[2], p0[3]);
    u0[2] = pkbf(p1[0], p1[1]);
    u0[3] = pkbf(p1[2], p1[3]);
    bf16x8 pa = __builtin_bit_cast(bf16x8, u0);

    // PV: A = P [m=i][k=j32], B = V^T [n=d][k=j] -> O[i][d]
#pragma unroll
    for (int c = 0; c < 4; c++) {
      bf16x8 v_ = *(const bf16x8*)(&Vs[(c * 16 + lm) * 72 + wj32 + q8]);
      oacc[c] = MFMA32(pa, v_, oacc[c]);
    }
    lacc = MFMA32(pa, bone, lacc);

    smw = nm;
    __syncthreads();  // end of iter: alt-buffer writes visible, cur reads done
  }

  // -------- epilogue: 2-way merge (wj partners) + distributed write --------
  if (lm == 0) {
#pragma unroll
    for (int r = 0; r < 4; r++)
      Lbuf[wj * 64 + wi16 + quad * 4 + r] = lacc[r];
  }
  if (wj == 1) {
#pragma unroll
    for (int c = 0; c < 4; c++)
#pragma unroll
      for (int r = 0; r < 4; r++)
        Om[(wi16 + quad * 4 + r) * 66 + c * 16 + lm] = oacc[c][r];
  }
  __syncthreads();
  if (wj == 0) {
#pragma unroll
    for (int c = 0; c < 4; c++)
#pragma unroll
      for (int r = 0; r < 4; r++)
        Om[(wi16 + quad * 4 + r) * 66 + c * 16 + lm] += oacc[c][r];
  }
  __syncthreads();
  // final write: wave w -> rows w*8..w*8+7; thread: 8 consecutive cols
  {
    int row = wave * 8 + (lane >> 3);
    int col = (lane & 7) * 8;
    float l = Lbuf[row] + Lbuf[64 + row];
    float inv = 1.0f / l;
    size_t idx = (size_t)(bidx * NA_ + i0 + row) * INNER_ + h * DH_ + col;
    ushort8_t gv = *(const ushort8_t*)(g + idx);
    ushort8_t oh, ol;
#pragma unroll
    for (int e = 0; e < 8; e++) {
      float o = Om[row * 66 + col + e];
      float gf = b2f((unsigned short)gv[e]);
      float sig = 1.0f / (1.0f + __expf(-gf));
      float val = o * inv * sig;
      unsigned short hb = bfbits(val);
      oh[e] = hb;
      ol[e] = bfbits(val - b2f(hb));
    }
    *(ushort8_t*)(gh + idx) = oh;
    *(ushort8_t*)(gl + idx) = ol;
  }
}

// ---------------- final GEMM in split-bf16 (hi/lo), 32x64 tiles, fp32 out -------
// R4 EXACT. LEDGER: B-direct-from-global variant (R9) = latency-bound, ~2x
// slower; the LDS double-buffer here hides L2 latency across k0 steps.
__global__ __launch_bounds__(256) void gemm_split_kernel(
    const bf16* __restrict__ Ah, const bf16* __restrict__ Al,
    const bf16* __restrict__ Bh, const bf16* __restrict__ Bl,
    const float* __restrict__ bias, float* __restrict__ C) {
  constexpr int K = 512, N = 256;
  __shared__ __align__(16) bf16 Ash[32 * 72];
  __shared__ __align__(16) bf16 Asl[32 * 72];
  __shared__ __align__(16) bf16 Bsh[64 * 72];
  __shared__ __align__(16) bf16 Bsl[64 * 72];
  int n0 = blockIdx.x * 64, m0 = blockIdx.y * 32;
  int t = threadIdx.x, wave = t >> 6, lane = t & 63;
  int lm = lane & 15, quad = lane >> 4, q8 = quad * 8;
  int wm = (wave & 1) * 16, wn = (wave >> 1) * 32;
  f32x4 acc[2] = {};
  for (int k0 = 0; k0 < K; k0 += 64) {
    __syncthreads();
    {
      int r = t >> 3, cg = t & 7;
      size_t ga = (size_t)(m0 + r) * K + k0 + cg * 8;
      *(ushort8_t*)(&Ash[r * 72 + cg * 8]) = *(const ushort8_t*)(Ah + ga);
      *(ushort8_t*)(&Asl[r * 72 + cg * 8]) = *(const ushort8_t*)(Al + ga);
    }
#pragma unroll
    for (int i = 0; i < 2; i++) {
      int id = t + 256 * i, r = id >> 3, cg = id & 7;
      size_t gb = (size_t)(n0 + r) * K + k0 + cg * 8;
      *(ushort8_t*)(&Bsh[r * 72 + cg * 8]) = *(const ushort8_t*)(Bh + gb);
      *(ushort8_t*)(&Bsl[r * 72 + cg * 8]) = *(const ushort8_t*)(Bl + gb);
    }
    __syncthreads();
#pragma unroll
    for (int kk = 0; kk < 64; kk += 32) {
      bf16x8 ah = *(const bf16x8*)(&Ash[(wm + lm) * 72 + kk + q8]);
      bf16x8 al = *(const bf16x8*)(&Asl[(wm + lm) * 72 + kk + q8]);
#pragma unroll
      for (int ni = 0; ni < 2; ni++) {
        bf16x8 bh_ = *(const bf16x8*)(&Bsh[(wn + ni * 16 + lm) * 72 + kk + q8]);
        bf16x8 bl_ = *(const bf16x8*)(&Bsl[(wn + ni * 16 + lm) * 72 + kk + q8]);
        acc[ni] = MFMA32(ah, bh_, acc[ni]);
        acc[ni] = MFMA32(ah, bl_, acc[ni]);
        acc[ni] = MFMA32(al, bh_, acc[ni]);
      }
    }
  }
#pragma unroll
  for (int ni = 0; ni < 2; ni++) {
    int n = n0 + wn + ni * 16 + lm;
    float bvv = bias[n];
    int mb = m0 + wm + quad * 4;
#pragma unroll
    for (int r = 0; r < 4; r++) C[(size_t)(mb + r) * N + n] = acc[ni][r] + bvv;
  }
}

extern "C" void kernel_launch(void* const* d_in, const int* in_sizes, int n_in,
                              void* d_out, int out_size, void* d_ws, size_t ws_size,
                              hipStream_t stream) {
  const float* feat_a = (const float*)d_in[0];
  const float* feat_b = (const float*)d_in[1];
  const void*  mask   = d_in[2];
  const float* Wq = (const float*)d_in[3];
  const float* bq = (const float*)d_in[4];
  const float* Wk = (const float*)d_in[5];
  const float* bk = (const float*)d_in[6];
  const float* Wv = (const float*)d_in[7];
  const float* bv = (const float*)d_in[8];
  const float* Wg = (const float*)d_in[9];
  const float* bg = (const float*)d_in[10];
  const float* Wo = (const float*)d_in[11];
  const float* bo = (const float*)d_in[12];
  const float* law = (const float*)d_in[13];
  const float* lab = (const float*)d_in[14];
  const float* lbw = (const float*)d_in[15];
  const float* lbb = (const float*)d_in[16];
  const float* qlw = (const float*)d_in[17];
  const float* qlb = (const float*)d_in[18];
  const float* klw = (const float*)d_in[19];
  const float* klb = (const float*)d_in[20];

  char* ws = (char*)d_ws;
  size_t off = 0;
  auto alloc = [&](size_t bytes) -> void* {
    void* p = ws + off;
    off += (bytes + 255) & ~(size_t)255;
    return p;
  };
  bf16* fa    = (bf16*)alloc((size_t)MROWS * 256 * 2);
  bf16* fb    = (bf16*)alloc((size_t)MROWS * 256 * 2);
  bf16* Wqt   = (bf16*)alloc((size_t)131072 * 2);
  bf16* Wkt   = (bf16*)alloc((size_t)131072 * 2);
  bf16* Wvt   = (bf16*)alloc((size_t)131072 * 2);
  bf16* Wgt   = (bf16*)alloc((size_t)131072 * 2);
  bf16* Woth  = (bf16*)alloc((size_t)131072 * 2);
  bf16* Wotl  = (bf16*)alloc((size_t)131072 * 2);
  bf16* qb_   = (bf16*)alloc((size_t)MROWS * 512 * 2);
  bf16* kb_   = (bf16*)alloc((size_t)MROWS * 512 * 2);
  bf16* vtb   = (bf16*)alloc((size_t)1024 * 2048 * 2);
  bf16* gbuf  = (bf16*)alloc((size_t)MROWS * 512 * 2);
  bf16* gh    = (bf16*)alloc((size_t)MROWS * 512 * 2);
  bf16* gl    = (bf16*)alloc((size_t)MROWS * 512 * 2);
  u64*  mbits = (u64*)alloc((size_t)131072 * 8);

  prep_kernel<<<6656, 256, 0, stream>>>(
      feat_a, feat_b, law, lab, lbw, lbb, fa, fb,
      Wq, Wk, Wv, Wg, Wo, Wqt, Wkt, Wvt, Wgt, Woth, Wotl, mask, mbits);
  gemm4_kernel<<<dim3(256, 1, 4), 256, 0, stream>>>(
      fa, fb, Wqt, Wkt, Wgt, Wvt, bq, bk, bg, bv,
      qlw, qlb, klw, klb, qb_, kb_, gbuf, vtb);
  attn_kernel<<<dim3(32, 16), 512, 0, stream>>>(qb_, kb_, vtb, gbuf, mbits, gh, gl);
  gemm_split_kernel<<<dim3(4, 128), 256, 0, stream>>>(gh, gl, Woth, Wotl, bo, (float*)d_out);
}